// Round 5
// baseline (16081.453 us; speedup 1.0000x reference)
//
#include <hip/hip_runtime.h>
#include <hip/hip_bf16.h>

// LBEBM R5: langevin fp32 with lane-consecutive-j mapping (conflict-free b128
// rows), per-thread-contiguous float4 weight streams (w1t/w2t/w2 rows) for
// latency hiding. Decoder unchanged (bf16 MFMA, R4-proven).

#define NTOT 65536

typedef __attribute__((ext_vector_type(8))) short bf16x8;
typedef __attribute__((ext_vector_type(4))) float f32x4;
typedef __attribute__((ext_vector_type(4))) unsigned short u16x4;

__device__ __forceinline__ unsigned short f2bf(float f) {
    union { float f; unsigned int u; } v; v.f = f;
    unsigned int r = v.u + 0x7fffu + ((v.u >> 16) & 1u);
    return (unsigned short)(r >> 16);
}
__device__ __forceinline__ float bf2f(unsigned short h) {
    union { unsigned int u; float f; } v; v.u = ((unsigned int)h) << 16;
    return v.f;
}
__device__ __forceinline__ void gelu_pair(float x, float& val, float& grad) {
    float cdf = 0.5f * (1.0f + erff(x * 0.70710678118654752440f));
    float pdf = 0.3989422804014326779f * __expf(-0.5f * x * x);
    val = x * cdf;
    grad = cdf + x * pdf;
}

// src[R][C] -> dst[C][R]
__global__ void transpose_f32(const float* __restrict__ src, float* __restrict__ dst,
                              int R, int C) {
    int idx = blockIdx.x * blockDim.x + threadIdx.x;
    if (idx < R * C) {
        int r = idx / C, c = idx - r * C;
        dst[c * R + r] = src[idx];
    }
}

// dst[n][k] (Nrows x Kp, bf16) = src[k][n] (K x Nsrc, f32), zero-padded.
__global__ void prep_wT_kernel(const float* __restrict__ src, unsigned short* __restrict__ dst,
                               int K, int Kp, int Nsrc, int Nrows) {
    int idx = blockIdx.x * blockDim.x + threadIdx.x;
    if (idx >= Nrows * Kp) return;
    int n = idx / Kp, k = idx - n * Kp;
    float v = (k < K && n < Nsrc) ? src[(size_t)k * Nsrc + n] : 0.f;
    dst[idx] = f2bf(v);
}

// ---------------- Langevin: 32 samples/wg, 512 threads, ~141KB LDS ----------------
__global__ __launch_bounds__(512) void langevin_kernel(
    const float* __restrict__ ftraj, const float* __restrict__ z0,
    const float* __restrict__ noise,
    const float* __restrict__ w1, const float* __restrict__ w1t,
    const float* __restrict__ b1,
    const float* __restrict__ w2, const float* __restrict__ w2t,
    const float* __restrict__ b2,
    const float* __restrict__ w3, const float* __restrict__ b3,
    float* __restrict__ zout)
{
    __shared__ float zcT[32][36];     // [k][s], k<16 z, k>=16 cond
    __shared__ float h1T[200][36];    // fwd h1; C/F split-K partials; D: dh2T
    __shared__ float h2T[200][36];    // fwd h2; E: dh1T
    __shared__ float d1T[200][36];    // gelu'(u1)
    __shared__ float d2T[200][36];    // gelu'(u2)
    __shared__ float g3T[20][36];     // -softmax(logits), [y][s]
    __shared__ float w3L[200][21];    // stride 21 (coprime 32): conflict-free cols
    __shared__ float b1L[200], b2L[200], b3L[20];

    const int tid = threadIdx.x;
    const int gbase = blockIdx.x * 32;
    const int s16 = tid >> 4, i16 = tid & 15;
    float* const sp = &h1T[0][0];

    for (int idx = tid; idx < 200 * 20; idx += 512) {
        int k = idx / 20, y = idx - k * 20;
        w3L[k][y] = w3[idx];
    }
    if (tid < 200) { b1L[tid] = b1[tid]; b2L[tid] = b2[tid]; }
    if (tid < 20)  { b3L[tid] = b3[tid]; }
    zcT[i16][s16]      = z0[(size_t)(gbase + s16) * 16 + i16];
    zcT[16 + i16][s16] = ftraj[(size_t)(gbase + s16) * 16 + i16];
    __syncthreads();

    float eps = noise[(size_t)(gbase + s16) * 16 + i16];

    const int jt = tid & 127;         // lane-consecutive j; active jt<100
    const int s0 = (tid >> 7) * 8;    // wave-uniform s-block
    const bool actJ = (jt < 100);

    for (int st = 0; st < 20; ++st) {
        float eps_next = 0.f;
        if (st < 19)
            eps_next = noise[((size_t)(st + 1) * NTOT + gbase + s16) * 16 + i16];

        // ---- A: u1 = [z|c] @ w1 + b1 (K=32); h1=gelu, d1=gelu' ----
        if (actJ) {
            const float* wr0 = w1t + (size_t)jt * 32;
            const float* wr1 = w1t + (size_t)(jt + 100) * 32;
            float acc[2][8];
            {
                float bb0 = b1L[jt], bb1 = b1L[jt + 100];
                #pragma unroll
                for (int ss = 0; ss < 8; ++ss) { acc[0][ss] = bb0; acc[1][ss] = bb1; }
            }
            #pragma unroll
            for (int kb = 0; kb < 8; ++kb) {
                const int k = kb * 4;
                float4 wa = *(const float4*)(wr0 + k);
                float4 wb = *(const float4*)(wr1 + k);
                const float wva[4] = {wa.x, wa.y, wa.z, wa.w};
                const float wvb[4] = {wb.x, wb.y, wb.z, wb.w};
                #pragma unroll
                for (int kk = 0; kk < 4; ++kk) {
                    const float4 zA = *(const float4*)&zcT[k + kk][s0];
                    const float4 zB = *(const float4*)&zcT[k + kk][s0 + 4];
                    acc[0][0] += wva[kk] * zA.x; acc[0][1] += wva[kk] * zA.y;
                    acc[0][2] += wva[kk] * zA.z; acc[0][3] += wva[kk] * zA.w;
                    acc[0][4] += wva[kk] * zB.x; acc[0][5] += wva[kk] * zB.y;
                    acc[0][6] += wva[kk] * zB.z; acc[0][7] += wva[kk] * zB.w;
                    acc[1][0] += wvb[kk] * zA.x; acc[1][1] += wvb[kk] * zA.y;
                    acc[1][2] += wvb[kk] * zA.z; acc[1][3] += wvb[kk] * zA.w;
                    acc[1][4] += wvb[kk] * zB.x; acc[1][5] += wvb[kk] * zB.y;
                    acc[1][6] += wvb[kk] * zB.z; acc[1][7] += wvb[kk] * zB.w;
                }
            }
            #pragma unroll
            for (int jj = 0; jj < 2; ++jj) {
                const int j = jt + jj * 100;
                float hv[8], dv[8];
                #pragma unroll
                for (int ss = 0; ss < 8; ++ss) gelu_pair(acc[jj][ss], hv[ss], dv[ss]);
                *(float4*)&h1T[j][s0]     = make_float4(hv[0], hv[1], hv[2], hv[3]);
                *(float4*)&h1T[j][s0 + 4] = make_float4(hv[4], hv[5], hv[6], hv[7]);
                *(float4*)&d1T[j][s0]     = make_float4(dv[0], dv[1], dv[2], dv[3]);
                *(float4*)&d1T[j][s0 + 4] = make_float4(dv[4], dv[5], dv[6], dv[7]);
            }
        }
        __syncthreads();

        // ---- B: u2 = h1 @ w2 + b2 (K=200); h2=gelu, d2=gelu' ----
        if (actJ) {
            const float* wr0 = w2t + (size_t)jt * 200;
            const float* wr1 = w2t + (size_t)(jt + 100) * 200;
            float acc[2][8];
            {
                float bb0 = b2L[jt], bb1 = b2L[jt + 100];
                #pragma unroll
                for (int ss = 0; ss < 8; ++ss) { acc[0][ss] = bb0; acc[1][ss] = bb1; }
            }
            #pragma unroll 4
            for (int kb = 0; kb < 50; ++kb) {
                const int k = kb * 4;
                float4 wa = *(const float4*)(wr0 + k);
                float4 wb = *(const float4*)(wr1 + k);
                const float wva[4] = {wa.x, wa.y, wa.z, wa.w};
                const float wvb[4] = {wb.x, wb.y, wb.z, wb.w};
                #pragma unroll
                for (int kk = 0; kk < 4; ++kk) {
                    const float4 hA = *(const float4*)&h1T[k + kk][s0];
                    const float4 hB = *(const float4*)&h1T[k + kk][s0 + 4];
                    acc[0][0] += wva[kk] * hA.x; acc[0][1] += wva[kk] * hA.y;
                    acc[0][2] += wva[kk] * hA.z; acc[0][3] += wva[kk] * hA.w;
                    acc[0][4] += wva[kk] * hB.x; acc[0][5] += wva[kk] * hB.y;
                    acc[0][6] += wva[kk] * hB.z; acc[0][7] += wva[kk] * hB.w;
                    acc[1][0] += wvb[kk] * hA.x; acc[1][1] += wvb[kk] * hA.y;
                    acc[1][2] += wvb[kk] * hA.z; acc[1][3] += wvb[kk] * hA.w;
                    acc[1][4] += wvb[kk] * hB.x; acc[1][5] += wvb[kk] * hB.y;
                    acc[1][6] += wvb[kk] * hB.z; acc[1][7] += wvb[kk] * hB.w;
                }
            }
            #pragma unroll
            for (int jj = 0; jj < 2; ++jj) {
                const int j = jt + jj * 100;
                float hv[8], dv[8];
                #pragma unroll
                for (int ss = 0; ss < 8; ++ss) gelu_pair(acc[jj][ss], hv[ss], dv[ss]);
                *(float4*)&h2T[j][s0]     = make_float4(hv[0], hv[1], hv[2], hv[3]);
                *(float4*)&h2T[j][s0 + 4] = make_float4(hv[4], hv[5], hv[6], hv[7]);
                *(float4*)&d2T[j][s0]     = make_float4(dv[0], dv[1], dv[2], dv[3]);
                *(float4*)&d2T[j][s0 + 4] = make_float4(dv[4], dv[5], dv[6], dv[7]);
            }
        }
        __syncthreads();

        // ---- C: logits partials (split-K 4x50) into sp ----
        {
            const int kc = tid >> 7;
            const int rc = tid & 127;
            const int sC0 = (rc >> 5) * 8;
            const int jC = rc & 31;
            if (jC < 20) {
                float acc[8] = {0, 0, 0, 0, 0, 0, 0, 0};
                #pragma unroll 2
                for (int k = kc * 50; k < kc * 50 + 50; ++k) {
                    float4 hA = *(const float4*)&h2T[k][sC0];
                    float4 hB = *(const float4*)&h2T[k][sC0 + 4];
                    float w = w3L[k][jC];
                    acc[0] += hA.x * w; acc[1] += hA.y * w;
                    acc[2] += hA.z * w; acc[3] += hA.w * w;
                    acc[4] += hB.x * w; acc[5] += hB.y * w;
                    acc[6] += hB.z * w; acc[7] += hB.w * w;
                }
                float* p = &sp[kc * 720 + jC * 36 + sC0];
                *(float4*)p       = make_float4(acc[0], acc[1], acc[2], acc[3]);
                *(float4*)(p + 4) = make_float4(acc[4], acc[5], acc[6], acc[7]);
            }
        }
        __syncthreads();

        // ---- combine + softmax ----
        if (tid < 32) {
            const int s = tid;
            float l[20];
            float m = -1e30f;
            #pragma unroll
            for (int y = 0; y < 20; ++y) {
                float v = b3L[y] + sp[y * 36 + s] + sp[720 + y * 36 + s]
                        + sp[1440 + y * 36 + s] + sp[2160 + y * 36 + s];
                l[y] = v;
                m = fmaxf(m, v);
            }
            float sum = 0.f;
            #pragma unroll
            for (int y = 0; y < 20; ++y) { l[y] = __expf(l[y] - m); sum += l[y]; }
            float inv = -1.0f / sum;
            #pragma unroll
            for (int y = 0; y < 20; ++y) g3T[y][s] = l[y] * inv;
        }
        __syncthreads();

        // ---- D: dh2T = (g3 @ w3^T) * d2 -> h1T (rows jt, jt+100) ----
        if (actJ) {
            const int k0 = jt, k1 = jt + 100;
            float acc[2][8] = {};
            #pragma unroll 4
            for (int y = 0; y < 20; ++y) {
                const float4 gA = *(const float4*)&g3T[y][s0];
                const float4 gB = *(const float4*)&g3T[y][s0 + 4];
                const float w0 = w3L[k0][y];
                const float w1v = w3L[k1][y];
                acc[0][0] += w0 * gA.x; acc[0][1] += w0 * gA.y;
                acc[0][2] += w0 * gA.z; acc[0][3] += w0 * gA.w;
                acc[0][4] += w0 * gB.x; acc[0][5] += w0 * gB.y;
                acc[0][6] += w0 * gB.z; acc[0][7] += w0 * gB.w;
                acc[1][0] += w1v * gA.x; acc[1][1] += w1v * gA.y;
                acc[1][2] += w1v * gA.z; acc[1][3] += w1v * gA.w;
                acc[1][4] += w1v * gB.x; acc[1][5] += w1v * gB.y;
                acc[1][6] += w1v * gB.z; acc[1][7] += w1v * gB.w;
            }
            #pragma unroll
            for (int kk = 0; kk < 2; ++kk) {
                const int k = kk ? k1 : k0;
                const float4 dA = *(const float4*)&d2T[k][s0];
                const float4 dB = *(const float4*)&d2T[k][s0 + 4];
                *(float4*)&h1T[k][s0] = make_float4(acc[kk][0] * dA.x, acc[kk][1] * dA.y,
                                                    acc[kk][2] * dA.z, acc[kk][3] * dA.w);
                *(float4*)&h1T[k][s0 + 4] = make_float4(acc[kk][4] * dB.x, acc[kk][5] * dB.y,
                                                        acc[kk][6] * dB.z, acc[kk][7] * dB.w);
            }
        }
        __syncthreads();

        // ---- E: dh1 = (dh2 @ w2^T) * d1 -> h2T (w2 rows, contiguous) ----
        if (actJ) {
            const float* wr0 = w2 + (size_t)jt * 200;
            const float* wr1 = w2 + (size_t)(jt + 100) * 200;
            float acc[2][8] = {};
            #pragma unroll 4
            for (int kb = 0; kb < 50; ++kb) {
                const int k = kb * 4;
                float4 wa = *(const float4*)(wr0 + k);
                float4 wb = *(const float4*)(wr1 + k);
                const float wva[4] = {wa.x, wa.y, wa.z, wa.w};
                const float wvb[4] = {wb.x, wb.y, wb.z, wb.w};
                #pragma unroll
                for (int kk = 0; kk < 4; ++kk) {
                    const float4 dA = *(const float4*)&h1T[k + kk][s0];
                    const float4 dB = *(const float4*)&h1T[k + kk][s0 + 4];
                    acc[0][0] += wva[kk] * dA.x; acc[0][1] += wva[kk] * dA.y;
                    acc[0][2] += wva[kk] * dA.z; acc[0][3] += wva[kk] * dA.w;
                    acc[0][4] += wva[kk] * dB.x; acc[0][5] += wva[kk] * dB.y;
                    acc[0][6] += wva[kk] * dB.z; acc[0][7] += wva[kk] * dB.w;
                    acc[1][0] += wvb[kk] * dA.x; acc[1][1] += wvb[kk] * dA.y;
                    acc[1][2] += wvb[kk] * dA.z; acc[1][3] += wvb[kk] * dA.w;
                    acc[1][4] += wvb[kk] * dB.x; acc[1][5] += wvb[kk] * dB.y;
                    acc[1][6] += wvb[kk] * dB.z; acc[1][7] += wvb[kk] * dB.w;
                }
            }
            #pragma unroll
            for (int jj = 0; jj < 2; ++jj) {
                const int j = jt + jj * 100;
                const float4 dA = *(const float4*)&d1T[j][s0];
                const float4 dB = *(const float4*)&d1T[j][s0 + 4];
                *(float4*)&h2T[j][s0] = make_float4(acc[jj][0] * dA.x, acc[jj][1] * dA.y,
                                                    acc[jj][2] * dA.z, acc[jj][3] * dA.w);
                *(float4*)&h2T[j][s0 + 4] = make_float4(acc[jj][4] * dB.x, acc[jj][5] * dB.y,
                                                        acc[jj][6] * dB.z, acc[jj][7] * dB.w);
            }
        }
        __syncthreads();

        // ---- F: gz partials (split-K 8x25) into sp; w1 rows L1-resident ----
        {
            const int kc = tid >> 6;
            const int rF = tid & 63;
            const int iF = rF >> 2;
            const int sF0 = (rF & 3) * 8;
            const float* wrow = w1 + (size_t)iF * 200;
            float acc[8] = {0, 0, 0, 0, 0, 0, 0, 0};
            #pragma unroll 5
            for (int k = kc * 25; k < kc * 25 + 25; ++k) {
                float4 dA = *(const float4*)&h2T[k][sF0];
                float4 dB = *(const float4*)&h2T[k][sF0 + 4];
                float w = wrow[k];
                acc[0] += dA.x * w; acc[1] += dA.y * w;
                acc[2] += dA.z * w; acc[3] += dA.w * w;
                acc[4] += dB.x * w; acc[5] += dB.y * w;
                acc[6] += dB.z * w; acc[7] += dB.w * w;
            }
            float* p = &sp[kc * 576 + iF * 36 + sF0];
            *(float4*)p       = make_float4(acc[0], acc[1], acc[2], acc[3]);
            *(float4*)(p + 4) = make_float4(acc[4], acc[5], acc[6], acc[7]);
        }
        __syncthreads();

        // ---- update z ----
        {
            float g = 0.f;
            #pragma unroll
            for (int kc = 0; kc < 8; ++kc) g += sp[kc * 576 + i16 * 36 + s16];
            float z = zcT[i16][s16];
            zcT[i16][s16] = z - 0.08f * (g + 0.25f * z) + 0.4f * eps;
            eps = eps_next;
        }
        __syncthreads();
    }

    zout[(size_t)(gbase + s16) * 16 + i16] = zcT[i16][s16];
}

// ---------------- Decoder: bf16 MFMA, 32 samples/wg, 512 threads ----------------
__global__ __launch_bounds__(512) void decoder_kernel(
    const float* __restrict__ ftraj, const float* __restrict__ zfin,
    const unsigned short* __restrict__ wT1, const unsigned short* __restrict__ wT2,
    const unsigned short* __restrict__ wT3, const unsigned short* __restrict__ wT4,
    const float* __restrict__ b1, const float* __restrict__ b2,
    const float* __restrict__ b3, const float* __restrict__ b4,
    float* __restrict__ out)
{
    __shared__ __align__(16) unsigned short xh[32][40];
    __shared__ __align__(16) unsigned short xl[32][40];
    __shared__ __align__(16) unsigned short hA[32][1032];
    __shared__ __align__(16) unsigned short hB[32][520];
    __shared__ float b1L[1024], b2L[512], b3L[1024];

    const int tid = threadIdx.x;
    const int gbase = blockIdx.x * 32;
    const int wv = tid >> 6, l = tid & 63;
    const int lr = l & 15, lg = l >> 4;

    for (int i = tid; i < 1024; i += 512) { b1L[i] = b1[i]; b3L[i] = b3[i]; }
    if (tid < 512) b2L[tid] = b2[tid];
    {
        int s = tid >> 4, c = tid & 15;
        float vf = ftraj[(size_t)(gbase + s) * 16 + c];
        unsigned short fh = f2bf(vf);
        xh[s][c] = fh;
        xl[s][c] = f2bf(vf - bf2f(fh));
        float vz = zfin[(size_t)(gbase + s) * 16 + c];
        unsigned short zh = f2bf(vz);
        xh[s][16 + c] = zh;
        xl[s][16 + c] = f2bf(vz - bf2f(zh));
    }
    __syncthreads();

    // L1: 32 -> 1024, hi/lo split input
    {
        bf16x8 xhf[2], xlf[2];
        #pragma unroll
        for (int mt = 0; mt < 2; ++mt) {
            xhf[mt] = *(const bf16x8*)&xh[mt * 16 + lr][lg * 8];
            xlf[mt] = *(const bf16x8*)&xl[mt * 16 + lr][lg * 8];
        }
        #pragma unroll 2
        for (int a = 0; a < 8; ++a) {
            const int nt = wv * 8 + a;
            bf16x8 af = *(const bf16x8*)&wT1[(size_t)(nt * 16 + lr) * 40 + lg * 8];
            f32x4 acc0 = {0.f, 0.f, 0.f, 0.f}, acc1 = {0.f, 0.f, 0.f, 0.f};
            acc0 = __builtin_amdgcn_mfma_f32_16x16x32_bf16(af, xhf[0], acc0, 0, 0, 0);
            acc0 = __builtin_amdgcn_mfma_f32_16x16x32_bf16(af, xlf[0], acc0, 0, 0, 0);
            acc1 = __builtin_amdgcn_mfma_f32_16x16x32_bf16(af, xhf[1], acc1, 0, 0, 0);
            acc1 = __builtin_amdgcn_mfma_f32_16x16x32_bf16(af, xlf[1], acc1, 0, 0, 0);
            const int n0 = nt * 16 + lg * 4;
            u16x4 o0, o1;
            #pragma unroll
            for (int r = 0; r < 4; ++r) {
                float bb = b1L[n0 + r];
                o0[r] = f2bf(fmaxf(acc0[r] + bb, 0.f));
                o1[r] = f2bf(fmaxf(acc1[r] + bb, 0.f));
            }
            *(u16x4*)&hA[lr][n0] = o0;
            *(u16x4*)&hA[16 + lr][n0] = o1;
        }
    }
    __syncthreads();

    // L2: 1024 -> 512
    {
        f32x4 acc[4][2];
        #pragma unroll
        for (int a = 0; a < 4; ++a)
            #pragma unroll
            for (int mt = 0; mt < 2; ++mt) acc[a][mt] = (f32x4){0.f, 0.f, 0.f, 0.f};
        #pragma unroll 2
        for (int ks = 0; ks < 32; ++ks) {
            const int k0 = ks * 32;
            bf16x8 bfr[2];
            #pragma unroll
            for (int mt = 0; mt < 2; ++mt)
                bfr[mt] = *(const bf16x8*)&hA[mt * 16 + lr][k0 + lg * 8];
            #pragma unroll
            for (int a = 0; a < 4; ++a) {
                const int n = (wv * 4 + a) * 16 + lr;
                bf16x8 af = *(const bf16x8*)&wT2[(size_t)n * 1032 + k0 + lg * 8];
                acc[a][0] = __builtin_amdgcn_mfma_f32_16x16x32_bf16(af, bfr[0], acc[a][0], 0, 0, 0);
                acc[a][1] = __builtin_amdgcn_mfma_f32_16x16x32_bf16(af, bfr[1], acc[a][1], 0, 0, 0);
            }
        }
        #pragma unroll
        for (int a = 0; a < 4; ++a) {
            const int n0 = (wv * 4 + a) * 16 + lg * 4;
            #pragma unroll
            for (int mt = 0; mt < 2; ++mt) {
                u16x4 o;
                #pragma unroll
                for (int r = 0; r < 4; ++r)
                    o[r] = f2bf(fmaxf(acc[a][mt][r] + b2L[n0 + r], 0.f));
                *(u16x4*)&hB[mt * 16 + lr][n0] = o;
            }
        }
    }
    __syncthreads();

    // L3: 512 -> 1024
    {
        f32x4 acc[8][2];
        #pragma unroll
        for (int a = 0; a < 8; ++a)
            #pragma unroll
            for (int mt = 0; mt < 2; ++mt) acc[a][mt] = (f32x4){0.f, 0.f, 0.f, 0.f};
        #pragma unroll 1
        for (int ks = 0; ks < 16; ++ks) {
            const int k0 = ks * 32;
            bf16x8 bfr[2];
            #pragma unroll
            for (int mt = 0; mt < 2; ++mt)
                bfr[mt] = *(const bf16x8*)&hB[mt * 16 + lr][k0 + lg * 8];
            #pragma unroll
            for (int a = 0; a < 8; ++a) {
                const int n = (wv * 8 + a) * 16 + lr;
                bf16x8 af = *(const bf16x8*)&wT3[(size_t)n * 520 + k0 + lg * 8];
                acc[a][0] = __builtin_amdgcn_mfma_f32_16x16x32_bf16(af, bfr[0], acc[a][0], 0, 0, 0);
                acc[a][1] = __builtin_amdgcn_mfma_f32_16x16x32_bf16(af, bfr[1], acc[a][1], 0, 0, 0);
            }
        }
        #pragma unroll
        for (int a = 0; a < 8; ++a) {
            const int n0 = (wv * 8 + a) * 16 + lg * 4;
            #pragma unroll
            for (int mt = 0; mt < 2; ++mt) {
                u16x4 o;
                #pragma unroll
                for (int r = 0; r < 4; ++r)
                    o[r] = f2bf(fmaxf(acc[a][mt][r] + b3L[n0 + r], 0.f));
                *(u16x4*)&hA[mt * 16 + lr][n0] = o;
            }
        }
    }
    __syncthreads();

    // L4: 1024 -> 10(pad 16), split-K over 8 waves
    float* pf = (float*)hB;
    {
        f32x4 acc[2];
        acc[0] = (f32x4){0.f, 0.f, 0.f, 0.f};
        acc[1] = (f32x4){0.f, 0.f, 0.f, 0.f};
        #pragma unroll
        for (int q = 0; q < 4; ++q) {
            const int k0 = (wv * 4 + q) * 32;
            bf16x8 af = *(const bf16x8*)&wT4[(size_t)lr * 1032 + k0 + lg * 8];
            #pragma unroll
            for (int mt = 0; mt < 2; ++mt) {
                bf16x8 bfr = *(const bf16x8*)&hA[mt * 16 + lr][k0 + lg * 8];
                acc[mt] = __builtin_amdgcn_mfma_f32_16x16x32_bf16(af, bfr, acc[mt], 0, 0, 0);
            }
        }
        #pragma unroll
        for (int mt = 0; mt < 2; ++mt)
            *(f32x4*)&pf[((wv * 2 + mt) * 64 + l) * 4] = acc[mt];
    }
    __syncthreads();
    {
        const int m = tid & 31, n = tid >> 5;
        const int lsrc = ((n >> 2) << 4) | (m & 15);
        const int r = n & 3, mt = m >> 4;
        float v = 0.f;
        #pragma unroll
        for (int w = 0; w < 8; ++w)
            v += pf[((w * 2 + mt) * 64 + lsrc) * 4 + r];
        if (n < 10)
            out[(size_t)(gbase + m) * 10 + n] = v + b4[n];
    }
}

__global__ void copy_ftraj_kernel(const float4* __restrict__ src, float4* __restrict__ dst) {
    int idx = blockIdx.x * blockDim.x + threadIdx.x;
    dst[idx] = src[idx];
}

extern "C" void kernel_launch(void* const* d_in, const int* in_sizes, int n_in,
                              void* d_out, int out_size, void* d_ws, size_t ws_size,
                              hipStream_t stream)
{
    const float* ftraj = (const float*)d_in[0];
    const float* z0    = (const float*)d_in[1];
    const float* noise = (const float*)d_in[2];
    const float* ew1 = (const float*)d_in[3];
    const float* eb1 = (const float*)d_in[4];
    const float* ew2 = (const float*)d_in[5];
    const float* eb2 = (const float*)d_in[6];
    const float* ew3 = (const float*)d_in[7];
    const float* eb3 = (const float*)d_in[8];
    const float* dw1 = (const float*)d_in[9];
    const float* db1 = (const float*)d_in[10];
    const float* dw2 = (const float*)d_in[11];
    const float* db2 = (const float*)d_in[12];
    const float* dw3 = (const float*)d_in[13];
    const float* db3 = (const float*)d_in[14];
    const float* dw4 = (const float*)d_in[15];
    const float* db4 = (const float*)d_in[16];
    float* out = (float*)d_out;

    char* ws = (char*)d_ws;
    float* w1t            = (float*)ws;                           // 25600 B
    float* w2t            = (float*)(ws + 32768);                 // 160000 B
    float* zfin           = (float*)(ws + 196608);                // 4 MB
    unsigned short* wsT1  = (unsigned short*)(ws + 4390912);      // 81920 B
    unsigned short* wsT2  = (unsigned short*)(ws + 4472832);      // 1056768 B
    unsigned short* wsT3  = (unsigned short*)(ws + 5529600);      // 1064960 B
    unsigned short* wsT4  = (unsigned short*)(ws + 6594560);      // 33024 B

    transpose_f32<<<(32 * 200 + 511) / 512, 512, 0, stream>>>(ew1, w1t, 32, 200);
    transpose_f32<<<(200 * 200 + 511) / 512, 512, 0, stream>>>(ew2, w2t, 200, 200);
    prep_wT_kernel<<<(1024 * 40 + 511) / 512, 512, 0, stream>>>(dw1, wsT1, 32, 40, 1024, 1024);
    prep_wT_kernel<<<(512 * 1032 + 511) / 512, 512, 0, stream>>>(dw2, wsT2, 1024, 1032, 512, 512);
    prep_wT_kernel<<<(1024 * 520 + 511) / 512, 512, 0, stream>>>(dw3, wsT3, 512, 520, 1024, 1024);
    prep_wT_kernel<<<(16 * 1032 + 511) / 512, 512, 0, stream>>>(dw4, wsT4, 1024, 1032, 10, 16);

    langevin_kernel<<<NTOT / 32, 512, 0, stream>>>(ftraj, z0, noise,
                                                   ew1, w1t, eb1,
                                                   ew2, w2t, eb2,
                                                   ew3, eb3, zfin);
    decoder_kernel<<<NTOT / 32, 512, 0, stream>>>(ftraj, zfin,
                                                  wsT1, wsT2, wsT3, wsT4,
                                                  db1, db2, db3, db4, out);
    copy_ftraj_kernel<<<512, 512, 0, stream>>>((const float4*)ftraj,
                                               (float4*)(out + (size_t)NTOT * 10));
}

// Round 6
// 3975.956 us; speedup vs baseline: 4.0447x; 4.0447x over previous
//
#include <hip/hip_runtime.h>
#include <hip/hip_bf16.h>

// LBEBM R6: langevin EBM fwd+bwd fully on bf16 MFMA with hi/lo double-bf16
// operands (3-term products ~= fp32). Decoder unchanged (R4-proven).

#define NTOT 65536

typedef __attribute__((ext_vector_type(8))) short bf16x8;
typedef __attribute__((ext_vector_type(4))) float f32x4;
typedef __attribute__((ext_vector_type(4))) unsigned short u16x4;

__device__ __forceinline__ unsigned short f2bf(float f) {
    union { float f; unsigned int u; } v; v.f = f;
    unsigned int r = v.u + 0x7fffu + ((v.u >> 16) & 1u);
    return (unsigned short)(r >> 16);
}
__device__ __forceinline__ float bf2f(unsigned short h) {
    union { unsigned int u; float f; } v; v.u = ((unsigned int)h) << 16;
    return v.f;
}
__device__ __forceinline__ void gelu_pair(float x, float& val, float& grad) {
    float cdf = 0.5f * (1.0f + erff(x * 0.70710678118654752440f));
    float pdf = 0.3989422804014326779f * __expf(-0.5f * x * x);
    val = x * cdf;
    grad = cdf + x * pdf;
}
__device__ __forceinline__ void mfma3(f32x4& acc, bf16x8 ah, bf16x8 al,
                                      bf16x8 bh, bf16x8 bl) {
    acc = __builtin_amdgcn_mfma_f32_16x16x32_bf16(ah, bh, acc, 0, 0, 0);
    acc = __builtin_amdgcn_mfma_f32_16x16x32_bf16(ah, bl, acc, 0, 0, 0);
    acc = __builtin_amdgcn_mfma_f32_16x16x32_bf16(al, bh, acc, 0, 0, 0);
}

// hi/lo bf16 fragment-layout prep: dst[n][k] (N x Kp). transposed: v=src[k][n].
__global__ void prep_hl(const float* __restrict__ src,
                        unsigned short* __restrict__ dh, unsigned short* __restrict__ dl,
                        int srcR, int srcC, int Kp, int total, int transposed) {
    int idx = blockIdx.x * blockDim.x + threadIdx.x;
    if (idx >= total) return;
    int n = idx / Kp, k = idx - n * Kp;
    float v = 0.f;
    if (transposed) { if (k < srcR && n < srcC) v = src[(size_t)k * srcC + n]; }
    else            { if (n < srcR && k < srcC) v = src[(size_t)n * srcC + k]; }
    unsigned short h = f2bf(v);
    dh[idx] = h;
    dl[idx] = f2bf(v - bf2f(h));
}

// dst[n][k] (Nrows x Kp, bf16) = src[k][n] (K x Nsrc, f32), zero-padded. (decoder)
__global__ void prep_wT_kernel(const float* __restrict__ src, unsigned short* __restrict__ dst,
                               int K, int Kp, int Nsrc, int Nrows) {
    int idx = blockIdx.x * blockDim.x + threadIdx.x;
    if (idx >= Nrows * Kp) return;
    int n = idx / Kp, k = idx - n * Kp;
    float v = (k < K && n < Nsrc) ? src[(size_t)k * Nsrc + n] : 0.f;
    dst[idx] = f2bf(v);
}

// ---------------- Langevin: 32 samples/wg, 512 threads (8 waves), ~139KB LDS --------
// MFMA convention (decoder-proven): A-frag = W[n][k] (lane: n=base+lr, k=k0+lg*8),
// B-frag = act[m][k] (lane: m=base+lr), D: lane r=0..3 -> (n=base+lg*4+r, m=base+lr).
__global__ __launch_bounds__(512) void langevin_kernel(
    const float* __restrict__ ftraj, const float* __restrict__ z0,
    const float* __restrict__ noise,
    const unsigned short* __restrict__ w1t_h, const unsigned short* __restrict__ w1t_l,
    const unsigned short* __restrict__ w2t_h, const unsigned short* __restrict__ w2t_l,
    const unsigned short* __restrict__ w2d_h, const unsigned short* __restrict__ w2d_l,
    const unsigned short* __restrict__ w3t_h, const unsigned short* __restrict__ w3t_l,
    const unsigned short* __restrict__ w3d_h, const unsigned short* __restrict__ w3d_l,
    const unsigned short* __restrict__ w1d_h, const unsigned short* __restrict__ w1d_l,
    const float* __restrict__ b1, const float* __restrict__ b2,
    const float* __restrict__ b3, float* __restrict__ zout)
{
    __shared__ float zF[32][17];                                 // fp32 z state
    __shared__ __align__(16) unsigned short zch[32][40], zcl[32][40];  // [s][k<32]
    __shared__ __align__(16) unsigned short g3h[32][40], g3l[32][40];  // [s][y<32]
    __shared__ __align__(16) unsigned short h1h[32][232], h1l[32][232]; // h1 / dh2
    __shared__ __align__(16) unsigned short h2h[32][232], h2l[32][232]; // h2 / dh1
    __shared__ float d1T[208][36], d2T[208][36];                 // gelu' (k-major)
    __shared__ float logitsT[20][36];
    __shared__ float gzT[16][36];
    __shared__ float b1L[208], b2L[208], b3L[20];

    const int tid = threadIdx.x;
    const int gbase = blockIdx.x * 32;
    const int s16 = tid >> 4, i16 = tid & 15;
    const int w = tid >> 6, lane = tid & 63;
    const int lr = lane & 15, lg = lane >> 4, lg8 = lg * 8;
    const int mt = w & 1, ng = (w >> 1) & 3;
    const int mrow = mt * 16 + lr;     // sample index this lane owns

    // zero padded k-columns of activation buffers (cols >=200 stay 0 forever
    // except 200..207 which epilogues rewrite as exact zeros)
    for (int i = tid; i < 32 * 232; i += 512) {
        int r = i / 232, c = i - r * 232;
        h1h[r][c] = 0; h1l[r][c] = 0; h2h[r][c] = 0; h2l[r][c] = 0;
    }
    if (tid < 208) {
        b1L[tid] = (tid < 200) ? b1[tid] : 0.f;
        b2L[tid] = (tid < 200) ? b2[tid] : 0.f;
    }
    if (tid < 20) b3L[tid] = b3[tid];
    {
        float zv = z0[(size_t)(gbase + s16) * 16 + i16];
        zF[s16][i16] = zv;
        unsigned short zh = f2bf(zv);
        zch[s16][i16] = zh;
        zcl[s16][i16] = f2bf(zv - bf2f(zh));
        float cv = ftraj[(size_t)(gbase + s16) * 16 + i16];
        unsigned short ch = f2bf(cv);
        zch[s16][16 + i16] = ch;
        zcl[s16][16 + i16] = f2bf(cv - bf2f(ch));
        // zc pad cols 32..39 never read by frags (k<32)
    }
    __syncthreads();

    float eps = noise[(size_t)(gbase + s16) * 16 + i16];

    for (int st = 0; st < 20; ++st) {
        float eps_next = (st < 19)
            ? noise[((size_t)(st + 1) * NTOT + gbase + s16) * 16 + i16] : 0.f;

        // ---- A: u1 = [z|c] @ w1, N=208(j), K=32 -> h1(hi/lo), d1T ----
        {
            bf16x8 Bh = *(const bf16x8*)&zch[mrow][lg8];
            bf16x8 Bl = *(const bf16x8*)&zcl[mrow][lg8];
            for (int nt = ng; nt < 13; nt += 4) {
                f32x4 acc = {0.f, 0.f, 0.f, 0.f};
                bf16x8 ah = *(const bf16x8*)&w1t_h[(nt * 16 + lr) * 32 + lg8];
                bf16x8 al = *(const bf16x8*)&w1t_l[(nt * 16 + lr) * 32 + lg8];
                mfma3(acc, ah, al, Bh, Bl);
                const int n0 = nt * 16 + lg * 4;
                u16x4 hh, hl;
                #pragma unroll
                for (int r = 0; r < 4; ++r) {
                    float u = acc[r] + b1L[n0 + r];
                    float hv, dv; gelu_pair(u, hv, dv);
                    unsigned short x = f2bf(hv);
                    hh[r] = x; hl[r] = f2bf(hv - bf2f(x));
                    d1T[n0 + r][mrow] = dv;
                }
                *(u16x4*)&h1h[mrow][n0] = hh;
                *(u16x4*)&h1l[mrow][n0] = hl;
            }
        }
        __syncthreads();

        // ---- B: u2 = h1 @ w2, N=208(j2), K=224 -> h2(hi/lo), d2T ----
        {
            bf16x8 Fh[7], Fl[7];
            #pragma unroll
            for (int kx = 0; kx < 7; ++kx) {
                Fh[kx] = *(const bf16x8*)&h1h[mrow][kx * 32 + lg8];
                Fl[kx] = *(const bf16x8*)&h1l[mrow][kx * 32 + lg8];
            }
            for (int nt = ng; nt < 13; nt += 4) {
                f32x4 acc = {0.f, 0.f, 0.f, 0.f};
                const unsigned short* ph = &w2t_h[(size_t)(nt * 16 + lr) * 224 + lg8];
                const unsigned short* pl = &w2t_l[(size_t)(nt * 16 + lr) * 224 + lg8];
                #pragma unroll
                for (int kx = 0; kx < 7; ++kx) {
                    bf16x8 ah = *(const bf16x8*)(ph + kx * 32);
                    bf16x8 al = *(const bf16x8*)(pl + kx * 32);
                    mfma3(acc, ah, al, Fh[kx], Fl[kx]);
                }
                const int n0 = nt * 16 + lg * 4;
                u16x4 hh, hl;
                #pragma unroll
                for (int r = 0; r < 4; ++r) {
                    float u = acc[r] + b2L[n0 + r];
                    float hv, dv; gelu_pair(u, hv, dv);
                    unsigned short x = f2bf(hv);
                    hh[r] = x; hl[r] = f2bf(hv - bf2f(x));
                    d2T[n0 + r][mrow] = dv;
                }
                *(u16x4*)&h2h[mrow][n0] = hh;
                *(u16x4*)&h2l[mrow][n0] = hl;
            }
        }
        __syncthreads();

        // ---- C: logits = h2 @ w3, N=32(y), K=224 -> logitsT (waves 0..3) ----
        if (w < 4) {
            const int mtC = w & 1, ntC = w >> 1;
            const int mrowC = mtC * 16 + lr;
            bf16x8 Fh[7], Fl[7];
            #pragma unroll
            for (int kx = 0; kx < 7; ++kx) {
                Fh[kx] = *(const bf16x8*)&h2h[mrowC][kx * 32 + lg8];
                Fl[kx] = *(const bf16x8*)&h2l[mrowC][kx * 32 + lg8];
            }
            f32x4 acc = {0.f, 0.f, 0.f, 0.f};
            const unsigned short* ph = &w3t_h[(size_t)(ntC * 16 + lr) * 224 + lg8];
            const unsigned short* pl = &w3t_l[(size_t)(ntC * 16 + lr) * 224 + lg8];
            #pragma unroll
            for (int kx = 0; kx < 7; ++kx) {
                bf16x8 ah = *(const bf16x8*)(ph + kx * 32);
                bf16x8 al = *(const bf16x8*)(pl + kx * 32);
                mfma3(acc, ah, al, Fh[kx], Fl[kx]);
            }
            const int n0 = ntC * 16 + lg * 4;
            #pragma unroll
            for (int r = 0; r < 4; ++r) {
                int y = n0 + r;
                if (y < 20) logitsT[y][mrowC] = acc[r] + b3L[y];
            }
        }
        __syncthreads();

        // ---- softmax: g3 = -softmax(logits), bf16 hi/lo [s][y pad 32] ----
        if (tid < 32) {
            const int s = tid;
            float l[20];
            float m = -1e30f;
            #pragma unroll
            for (int y = 0; y < 20; ++y) { l[y] = logitsT[y][s]; m = fmaxf(m, l[y]); }
            float sum = 0.f;
            #pragma unroll
            for (int y = 0; y < 20; ++y) { l[y] = __expf(l[y] - m); sum += l[y]; }
            float inv = -1.0f / sum;
            #pragma unroll
            for (int y = 0; y < 32; ++y) {
                float gv = (y < 20) ? l[y] * inv : 0.f;
                unsigned short gh = f2bf(gv);
                g3h[s][y] = gh;
                g3l[s][y] = f2bf(gv - bf2f(gh));
            }
        }
        __syncthreads();

        // ---- D: dh2 = (g3 @ w3^T) * d2, N=208(k2), K=32 -> h1 buffers ----
        {
            bf16x8 Bh = *(const bf16x8*)&g3h[mrow][lg8];
            bf16x8 Bl = *(const bf16x8*)&g3l[mrow][lg8];
            for (int nt = ng; nt < 13; nt += 4) {
                f32x4 acc = {0.f, 0.f, 0.f, 0.f};
                bf16x8 ah = *(const bf16x8*)&w3d_h[(nt * 16 + lr) * 32 + lg8];
                bf16x8 al = *(const bf16x8*)&w3d_l[(nt * 16 + lr) * 32 + lg8];
                mfma3(acc, ah, al, Bh, Bl);
                const int n0 = nt * 16 + lg * 4;
                u16x4 vh, vl;
                #pragma unroll
                for (int r = 0; r < 4; ++r) {
                    float v = acc[r] * d2T[n0 + r][mrow];
                    unsigned short x = f2bf(v);
                    vh[r] = x; vl[r] = f2bf(v - bf2f(x));
                }
                *(u16x4*)&h1h[mrow][n0] = vh;   // dh2
                *(u16x4*)&h1l[mrow][n0] = vl;
            }
        }
        __syncthreads();

        // ---- E: dh1 = (dh2 @ w2^T) * d1, N=208(i), K=224 -> h2 buffers ----
        {
            bf16x8 Fh[7], Fl[7];
            #pragma unroll
            for (int kx = 0; kx < 7; ++kx) {
                Fh[kx] = *(const bf16x8*)&h1h[mrow][kx * 32 + lg8];
                Fl[kx] = *(const bf16x8*)&h1l[mrow][kx * 32 + lg8];
            }
            for (int nt = ng; nt < 13; nt += 4) {
                f32x4 acc = {0.f, 0.f, 0.f, 0.f};
                const unsigned short* ph = &w2d_h[(size_t)(nt * 16 + lr) * 224 + lg8];
                const unsigned short* pl = &w2d_l[(size_t)(nt * 16 + lr) * 224 + lg8];
                #pragma unroll
                for (int kx = 0; kx < 7; ++kx) {
                    bf16x8 ah = *(const bf16x8*)(ph + kx * 32);
                    bf16x8 al = *(const bf16x8*)(pl + kx * 32);
                    mfma3(acc, ah, al, Fh[kx], Fl[kx]);
                }
                const int n0 = nt * 16 + lg * 4;
                u16x4 vh, vl;
                #pragma unroll
                for (int r = 0; r < 4; ++r) {
                    float v = acc[r] * d1T[n0 + r][mrow];
                    unsigned short x = f2bf(v);
                    vh[r] = x; vl[r] = f2bf(v - bf2f(x));
                }
                *(u16x4*)&h2h[mrow][n0] = vh;   // dh1
                *(u16x4*)&h2l[mrow][n0] = vl;
            }
        }
        __syncthreads();

        // ---- F: gz = dh1 @ w1[:16]^T, N=16, K=224 (waves 0,1) ----
        if (w < 2) {
            const int mrowF = w * 16 + lr;
            bf16x8 Fh[7], Fl[7];
            #pragma unroll
            for (int kx = 0; kx < 7; ++kx) {
                Fh[kx] = *(const bf16x8*)&h2h[mrowF][kx * 32 + lg8];
                Fl[kx] = *(const bf16x8*)&h2l[mrowF][kx * 32 + lg8];
            }
            f32x4 acc = {0.f, 0.f, 0.f, 0.f};
            const unsigned short* ph = &w1d_h[(size_t)lr * 224 + lg8];
            const unsigned short* pl = &w1d_l[(size_t)lr * 224 + lg8];
            #pragma unroll
            for (int kx = 0; kx < 7; ++kx) {
                bf16x8 ah = *(const bf16x8*)(ph + kx * 32);
                bf16x8 al = *(const bf16x8*)(pl + kx * 32);
                mfma3(acc, ah, al, Fh[kx], Fl[kx]);
            }
            #pragma unroll
            for (int r = 0; r < 4; ++r)
                gzT[lg * 4 + r][mrowF] = acc[r];
        }
        __syncthreads();

        // ---- update z ----
        {
            float g = gzT[i16][s16];
            float z = zF[s16][i16];
            float zn = z - 0.08f * (g + 0.25f * z) + 0.4f * eps;
            zF[s16][i16] = zn;
            unsigned short zh2 = f2bf(zn);
            zch[s16][i16] = zh2;
            zcl[s16][i16] = f2bf(zn - bf2f(zh2));
            eps = eps_next;
        }
        __syncthreads();
    }

    zout[(size_t)(gbase + s16) * 16 + i16] = zF[s16][i16];
}

// ---------------- Decoder: bf16 MFMA, 32 samples/wg, 512 threads (R4) -------------
__global__ __launch_bounds__(512) void decoder_kernel(
    const float* __restrict__ ftraj, const float* __restrict__ zfin,
    const unsigned short* __restrict__ wT1, const unsigned short* __restrict__ wT2,
    const unsigned short* __restrict__ wT3, const unsigned short* __restrict__ wT4,
    const float* __restrict__ b1, const float* __restrict__ b2,
    const float* __restrict__ b3, const float* __restrict__ b4,
    float* __restrict__ out)
{
    __shared__ __align__(16) unsigned short xh[32][40];
    __shared__ __align__(16) unsigned short xl[32][40];
    __shared__ __align__(16) unsigned short hA[32][1032];
    __shared__ __align__(16) unsigned short hB[32][520];
    __shared__ float b1L[1024], b2L[512], b3L[1024];

    const int tid = threadIdx.x;
    const int gbase = blockIdx.x * 32;
    const int wv = tid >> 6, l = tid & 63;
    const int lr = l & 15, lg = l >> 4;

    for (int i = tid; i < 1024; i += 512) { b1L[i] = b1[i]; b3L[i] = b3[i]; }
    if (tid < 512) b2L[tid] = b2[tid];
    {
        int s = tid >> 4, c = tid & 15;
        float vf = ftraj[(size_t)(gbase + s) * 16 + c];
        unsigned short fh = f2bf(vf);
        xh[s][c] = fh;
        xl[s][c] = f2bf(vf - bf2f(fh));
        float vz = zfin[(size_t)(gbase + s) * 16 + c];
        unsigned short zh = f2bf(vz);
        xh[s][16 + c] = zh;
        xl[s][16 + c] = f2bf(vz - bf2f(zh));
    }
    __syncthreads();

    // L1: 32 -> 1024, hi/lo split input
    {
        bf16x8 xhf[2], xlf[2];
        #pragma unroll
        for (int mt = 0; mt < 2; ++mt) {
            xhf[mt] = *(const bf16x8*)&xh[mt * 16 + lr][lg * 8];
            xlf[mt] = *(const bf16x8*)&xl[mt * 16 + lr][lg * 8];
        }
        #pragma unroll 2
        for (int a = 0; a < 8; ++a) {
            const int nt = wv * 8 + a;
            bf16x8 af = *(const bf16x8*)&wT1[(size_t)(nt * 16 + lr) * 40 + lg * 8];
            f32x4 acc0 = {0.f, 0.f, 0.f, 0.f}, acc1 = {0.f, 0.f, 0.f, 0.f};
            acc0 = __builtin_amdgcn_mfma_f32_16x16x32_bf16(af, xhf[0], acc0, 0, 0, 0);
            acc0 = __builtin_amdgcn_mfma_f32_16x16x32_bf16(af, xlf[0], acc0, 0, 0, 0);
            acc1 = __builtin_amdgcn_mfma_f32_16x16x32_bf16(af, xhf[1], acc1, 0, 0, 0);
            acc1 = __builtin_amdgcn_mfma_f32_16x16x32_bf16(af, xlf[1], acc1, 0, 0, 0);
            const int n0 = nt * 16 + lg * 4;
            u16x4 o0, o1;
            #pragma unroll
            for (int r = 0; r < 4; ++r) {
                float bb = b1L[n0 + r];
                o0[r] = f2bf(fmaxf(acc0[r] + bb, 0.f));
                o1[r] = f2bf(fmaxf(acc1[r] + bb, 0.f));
            }
            *(u16x4*)&hA[lr][n0] = o0;
            *(u16x4*)&hA[16 + lr][n0] = o1;
        }
    }
    __syncthreads();

    // L2: 1024 -> 512
    {
        f32x4 acc[4][2];
        #pragma unroll
        for (int a = 0; a < 4; ++a)
            #pragma unroll
            for (int mt = 0; mt < 2; ++mt) acc[a][mt] = (f32x4){0.f, 0.f, 0.f, 0.f};
        #pragma unroll 2
        for (int ks = 0; ks < 32; ++ks) {
            const int k0 = ks * 32;
            bf16x8 bfr[2];
            #pragma unroll
            for (int mt = 0; mt < 2; ++mt)
                bfr[mt] = *(const bf16x8*)&hA[mt * 16 + lr][k0 + lg * 8];
            #pragma unroll
            for (int a = 0; a < 4; ++a) {
                const int n = (wv * 4 + a) * 16 + lr;
                bf16x8 af = *(const bf16x8*)&wT2[(size_t)n * 1032 + k0 + lg * 8];
                acc[a][0] = __builtin_amdgcn_mfma_f32_16x16x32_bf16(af, bfr[0], acc[a][0], 0, 0, 0);
                acc[a][1] = __builtin_amdgcn_mfma_f32_16x16x32_bf16(af, bfr[1], acc[a][1], 0, 0, 0);
            }
        }
        #pragma unroll
        for (int a = 0; a < 4; ++a) {
            const int n0 = (wv * 4 + a) * 16 + lg * 4;
            #pragma unroll
            for (int mt = 0; mt < 2; ++mt) {
                u16x4 o;
                #pragma unroll
                for (int r = 0; r < 4; ++r)
                    o[r] = f2bf(fmaxf(acc[a][mt][r] + b2L[n0 + r], 0.f));
                *(u16x4*)&hB[mt * 16 + lr][n0] = o;
            }
        }
    }
    __syncthreads();

    // L3: 512 -> 1024
    {
        f32x4 acc[8][2];
        #pragma unroll
        for (int a = 0; a < 8; ++a)
            #pragma unroll
            for (int mt = 0; mt < 2; ++mt) acc[a][mt] = (f32x4){0.f, 0.f, 0.f, 0.f};
        #pragma unroll 1
        for (int ks = 0; ks < 16; ++ks) {
            const int k0 = ks * 32;
            bf16x8 bfr[2];
            #pragma unroll
            for (int mt = 0; mt < 2; ++mt)
                bfr[mt] = *(const bf16x8*)&hB[mt * 16 + lr][k0 + lg * 8];
            #pragma unroll
            for (int a = 0; a < 8; ++a) {
                const int n = (wv * 8 + a) * 16 + lr;
                bf16x8 af = *(const bf16x8*)&wT3[(size_t)n * 520 + k0 + lg * 8];
                acc[a][0] = __builtin_amdgcn_mfma_f32_16x16x32_bf16(af, bfr[0], acc[a][0], 0, 0, 0);
                acc[a][1] = __builtin_amdgcn_mfma_f32_16x16x32_bf16(af, bfr[1], acc[a][1], 0, 0, 0);
            }
        }
        #pragma unroll
        for (int a = 0; a < 8; ++a) {
            const int n0 = (wv * 8 + a) * 16 + lg * 4;
            #pragma unroll
            for (int mt = 0; mt < 2; ++mt) {
                u16x4 o;
                #pragma unroll
                for (int r = 0; r < 4; ++r)
                    o[r] = f2bf(fmaxf(acc[a][mt][r] + b3L[n0 + r], 0.f));
                *(u16x4*)&hA[mt * 16 + lr][n0] = o;
            }
        }
    }
    __syncthreads();

    // L4: 1024 -> 10(pad 16), split-K over 8 waves
    float* pf = (float*)hB;
    {
        f32x4 acc[2];
        acc[0] = (f32x4){0.f, 0.f, 0.f, 0.f};
        acc[1] = (f32x4){0.f, 0.f, 0.f, 0.f};
        #pragma unroll
        for (int q = 0; q < 4; ++q) {
            const int k0 = (wv * 4 + q) * 32;
            bf16x8 af = *(const bf16x8*)&wT4[(size_t)lr * 1032 + k0 + lg * 8];
            #pragma unroll
            for (int mt = 0; mt < 2; ++mt) {
                bf16x8 bfr = *(const bf16x8*)&hA[mt * 16 + lr][k0 + lg * 8];
                acc[mt] = __builtin_amdgcn_mfma_f32_16x16x32_bf16(af, bfr, acc[mt], 0, 0, 0);
            }
        }
        #pragma unroll
        for (int mt = 0; mt < 2; ++mt)
            *(f32x4*)&pf[((wv * 2 + mt) * 64 + l) * 4] = acc[mt];
    }
    __syncthreads();
    {
        const int m = tid & 31, n = tid >> 5;
        const int lsrc = ((n >> 2) << 4) | (m & 15);
        const int r = n & 3, mt = m >> 4;
        float v = 0.f;
        #pragma unroll
        for (int ww = 0; ww < 8; ++ww)
            v += pf[((ww * 2 + mt) * 64 + lsrc) * 4 + r];
        if (n < 10)
            out[(size_t)(gbase + m) * 10 + n] = v + b4[n];
    }
}

__global__ void copy_ftraj_kernel(const float4* __restrict__ src, float4* __restrict__ dst) {
    int idx = blockIdx.x * blockDim.x + threadIdx.x;
    dst[idx] = src[idx];
}

extern "C" void kernel_launch(void* const* d_in, const int* in_sizes, int n_in,
                              void* d_out, int out_size, void* d_ws, size_t ws_size,
                              hipStream_t stream)
{
    const float* ftraj = (const float*)d_in[0];
    const float* z0    = (const float*)d_in[1];
    const float* noise = (const float*)d_in[2];
    const float* ew1 = (const float*)d_in[3];
    const float* eb1 = (const float*)d_in[4];
    const float* ew2 = (const float*)d_in[5];
    const float* eb2 = (const float*)d_in[6];
    const float* ew3 = (const float*)d_in[7];
    const float* eb3 = (const float*)d_in[8];
    const float* dw1 = (const float*)d_in[9];
    const float* db1 = (const float*)d_in[10];
    const float* dw2 = (const float*)d_in[11];
    const float* db2 = (const float*)d_in[12];
    const float* dw3 = (const float*)d_in[13];
    const float* db3 = (const float*)d_in[14];
    const float* dw4 = (const float*)d_in[15];
    const float* db4 = (const float*)d_in[16];
    float* out = (float*)d_out;

    char* ws = (char*)d_ws;
    float* zfin = (float*)ws;                                       // 4 MB
    unsigned short* w1t_h = (unsigned short*)(ws + 4194304);        // 13312 B
    unsigned short* w1t_l = (unsigned short*)(ws + 4208640);
    unsigned short* w2t_h = (unsigned short*)(ws + 4222976);        // 93184 B
    unsigned short* w2t_l = (unsigned short*)(ws + 4317184);
    unsigned short* w2d_h = (unsigned short*)(ws + 4411392);
    unsigned short* w2d_l = (unsigned short*)(ws + 4505600);
    unsigned short* w3t_h = (unsigned short*)(ws + 4599808);        // 14336 B
    unsigned short* w3t_l = (unsigned short*)(ws + 4615168);
    unsigned short* w3d_h = (unsigned short*)(ws + 4630528);        // 13312 B
    unsigned short* w3d_l = (unsigned short*)(ws + 4644864);
    unsigned short* w1d_h = (unsigned short*)(ws + 4659200);        // 7168 B
    unsigned short* w1d_l = (unsigned short*)(ws + 4667392);
    unsigned short* wsT1  = (unsigned short*)(ws + 4675584);        // 81920 B
    unsigned short* wsT2  = (unsigned short*)(ws + 4757504);        // 1056768 B
    unsigned short* wsT3  = (unsigned short*)(ws + 5814272);        // 1064960 B
    unsigned short* wsT4  = (unsigned short*)(ws + 6879232);        // 33024 B

    // EBM weight fragment arrays (hi/lo):
    prep_hl<<<(208*32 + 511)/512, 512, 0, stream>>>(ew1, w1t_h, w1t_l, 32, 200, 32, 208*32, 1);
    prep_hl<<<(208*224 + 511)/512, 512, 0, stream>>>(ew2, w2t_h, w2t_l, 200, 200, 224, 208*224, 1);
    prep_hl<<<(208*224 + 511)/512, 512, 0, stream>>>(ew2, w2d_h, w2d_l, 200, 200, 224, 208*224, 0);
    prep_hl<<<(32*224 + 511)/512, 512, 0, stream>>>(ew3, w3t_h, w3t_l, 200, 20, 224, 32*224, 1);
    prep_hl<<<(208*32 + 511)/512, 512, 0, stream>>>(ew3, w3d_h, w3d_l, 200, 20, 32, 208*32, 0);
    prep_hl<<<(16*224 + 511)/512, 512, 0, stream>>>(ew1, w1d_h, w1d_l, 32, 200, 224, 16*224, 0);
    // decoder weights:
    prep_wT_kernel<<<(1024*40 + 511)/512, 512, 0, stream>>>(dw1, wsT1, 32, 40, 1024, 1024);
    prep_wT_kernel<<<(512*1032 + 511)/512, 512, 0, stream>>>(dw2, wsT2, 1024, 1032, 512, 512);
    prep_wT_kernel<<<(1024*520 + 511)/512, 512, 0, stream>>>(dw3, wsT3, 512, 520, 1024, 1024);
    prep_wT_kernel<<<(16*1032 + 511)/512, 512, 0, stream>>>(dw4, wsT4, 1024, 1032, 10, 16);

    langevin_kernel<<<NTOT / 32, 512, 0, stream>>>(
        ftraj, z0, noise,
        w1t_h, w1t_l, w2t_h, w2t_l, w2d_h, w2d_l,
        w3t_h, w3t_l, w3d_h, w3d_l, w1d_h, w1d_l,
        eb1, eb2, eb3, zfin);
    decoder_kernel<<<NTOT / 32, 512, 0, stream>>>(ftraj, zfin,
                                                  wsT1, wsT2, wsT3, wsT4,
                                                  db1, db2, db3, db4, out);
    copy_ftraj_kernel<<<512, 512, 0, stream>>>((const float4*)ftraj,
                                               (float4*)(out + (size_t)NTOT * 10));
}

// Round 7
// 1505.712 us; speedup vs baseline: 10.6803x; 2.6406x over previous
//
#include <hip/hip_runtime.h>
#include <hip/hip_bf16.h>

// LBEBM R7: langevin EBM in single fp16 MFMA (z state fp32, z input hi/lo),
// wave-packed weight fragments (coalesced 1KB/wave loads), 78KB LDS -> 2 wg/CU,
// all 8 waves active in every phase. Decoder unchanged (bf16 MFMA, R4-proven).

#define NTOT 65536

typedef __attribute__((ext_vector_type(8))) _Float16 f16x8;
typedef __attribute__((ext_vector_type(8))) short bf16x8;
typedef __attribute__((ext_vector_type(4))) float f32x4;
typedef __attribute__((ext_vector_type(4))) unsigned short u16x4;

__device__ __forceinline__ unsigned short f2bf(float f) {
    union { float f; unsigned int u; } v; v.f = f;
    unsigned int r = v.u + 0x7fffu + ((v.u >> 16) & 1u);
    return (unsigned short)(r >> 16);
}
__device__ __forceinline__ float bf2f(unsigned short h) {
    union { unsigned int u; float f; } v; v.u = ((unsigned int)h) << 16;
    return v.f;
}
__device__ __forceinline__ unsigned short f2h(float f) {
    union { _Float16 h; unsigned short u; } v; v.h = (_Float16)f; return v.u;
}
__device__ __forceinline__ float h2f(unsigned short u) {
    union { unsigned short u; _Float16 h; } v; v.u = u; return (float)v.h;
}
__device__ __forceinline__ void gelu_pair(float x, float& val, float& grad) {
    float cdf = 0.5f * (1.0f + erff(x * 0.70710678118654752440f));
    float pdf = 0.3989422804014326779f * __expf(-0.5f * x * x);
    val = x * cdf;
    grad = cdf + x * pdf;
}

// Wave-packed fp16 weight fragments: dst[((nt*KT+kt)*64+lane)*8+e] holds
// W[n=nt*16+(lane&15)][k=kt*32+(lane>>4)*8+e] (transposed: src[k][n]).
__global__ void pack_w(const float* __restrict__ src, unsigned short* __restrict__ dst,
                       int srcR, int srcC, int transposed, int NT, int KT) {
    int idx = blockIdx.x * blockDim.x + threadIdx.x;
    int total = NT * KT * 512;
    if (idx >= total) return;
    int e = idx & 7, lane = (idx >> 3) & 63, t = idx >> 9;
    int kt = t % KT, nt = t / KT;
    int n = nt * 16 + (lane & 15);
    int k = kt * 32 + (lane >> 4) * 8 + e;
    float v = 0.f;
    if (transposed) { if (k < srcR && n < srcC) v = src[(size_t)k * srcC + n]; }
    else            { if (n < srcR && k < srcC) v = src[(size_t)n * srcC + k]; }
    dst[idx] = f2h(v);
}

// dst[n][k] (Nrows x Kp, bf16) = src[k][n] (K x Nsrc, f32), zero-padded. (decoder)
__global__ void prep_wT_kernel(const float* __restrict__ src, unsigned short* __restrict__ dst,
                               int K, int Kp, int Nsrc, int Nrows) {
    int idx = blockIdx.x * blockDim.x + threadIdx.x;
    if (idx >= Nrows * Kp) return;
    int n = idx / Kp, k = idx - n * Kp;
    float v = (k < K && n < Nsrc) ? src[(size_t)k * Nsrc + n] : 0.f;
    dst[idx] = f2bf(v);
}

// ---------------- Langevin: 32 samples/wg, 512 threads, ~78.5KB LDS, 2 wg/CU ------
__global__ __launch_bounds__(512, 4) void langevin_kernel(
    const float* __restrict__ ftraj, const float* __restrict__ z0,
    const float* __restrict__ noise,
    const unsigned short* __restrict__ w1tp, const unsigned short* __restrict__ w2tp,
    const unsigned short* __restrict__ w2dp, const unsigned short* __restrict__ w3tp,
    const unsigned short* __restrict__ w3dp, const unsigned short* __restrict__ w1dp,
    const float* __restrict__ b1, const float* __restrict__ b2,
    const float* __restrict__ b3, float* __restrict__ zout)
{
    __shared__ __align__(16) unsigned short zcH[32][40], zcL[32][40]; // [s][k<32]
    __shared__ __align__(16) unsigned short g3H[32][40];              // -softmax
    __shared__ __align__(16) unsigned short h1H[32][232];             // h1 / dh2
    __shared__ __align__(16) unsigned short h2H[32][232];             // h2 / dh1
    __shared__ __align__(16) unsigned short d1T[208][40];             // gelu'(u1); F: gzP alias
    __shared__ __align__(16) unsigned short d2T[208][40];             // gelu'(u2)
    __shared__ float logitsP[2][20][36];
    __shared__ float zF[32][17];
    __shared__ float b1L[208], b2L[208], b3L[20];

    float (*gzP)[16][36] = (float (*)[16][36])&d1T[0][0];  // 9216B <= 16640B

    const int tid = threadIdx.x;
    const int gbase = blockIdx.x * 32;
    const int s16 = tid >> 4, i16 = tid & 15;
    const int w = tid >> 6, lane = tid & 63;
    const int lr = lane & 15, lg = lane >> 4, lg8 = lg * 8;
    const int mt = w & 1, ng = (w >> 1) & 3;
    const int mrow = mt * 16 + lr;

    const f16x8* W1T = (const f16x8*)w1tp;
    const f16x8* W2T = (const f16x8*)w2tp;
    const f16x8* W2D = (const f16x8*)w2dp;
    const f16x8* W3T = (const f16x8*)w3tp;
    const f16x8* W3D = (const f16x8*)w3dp;
    const f16x8* W1D = (const f16x8*)w1dp;

    // zero pad cols of h buffers (208..231 never written by epilogues)
    for (int i = tid; i < 32 * 232; i += 512) {
        int r = i / 232, c = i - r * 232;
        h1H[r][c] = 0; h2H[r][c] = 0;
    }
    if (tid < 208) {
        b1L[tid] = (tid < 200) ? b1[tid] : 0.f;
        b2L[tid] = (tid < 200) ? b2[tid] : 0.f;
    }
    if (tid < 20) b3L[tid] = b3[tid];
    {
        float zv = z0[(size_t)(gbase + s16) * 16 + i16];
        zF[s16][i16] = zv;
        unsigned short zh = f2h(zv);
        zcH[s16][i16] = zh;
        zcL[s16][i16] = f2h(zv - h2f(zh));
        float cv = ftraj[(size_t)(gbase + s16) * 16 + i16];
        unsigned short ch = f2h(cv);
        zcH[s16][16 + i16] = ch;
        zcL[s16][16 + i16] = f2h(cv - h2f(ch));
    }
    __syncthreads();

    float eps = noise[(size_t)(gbase + s16) * 16 + i16];

    for (int st = 0; st < 20; ++st) {
        float eps_next = (st < 19)
            ? noise[((size_t)(st + 1) * NTOT + gbase + s16) * 16 + i16] : 0.f;

        // ---- A: u1 = [z|c] @ w1 + b1, N=208, K=32 (z hi/lo) ----
        {
            f16x8 Bh = *(const f16x8*)&zcH[mrow][lg8];
            f16x8 Bl = *(const f16x8*)&zcL[mrow][lg8];
            for (int nt = ng; nt < 13; nt += 4) {
                f32x4 acc = {0.f, 0.f, 0.f, 0.f};
                f16x8 af = W1T[nt * 64 + lane];
                acc = __builtin_amdgcn_mfma_f32_16x16x32_f16(af, Bh, acc, 0, 0, 0);
                acc = __builtin_amdgcn_mfma_f32_16x16x32_f16(af, Bl, acc, 0, 0, 0);
                const int n0 = nt * 16 + lg * 4;
                u16x4 hh;
                #pragma unroll
                for (int r = 0; r < 4; ++r) {
                    float hv, dv;
                    gelu_pair(acc[r] + b1L[n0 + r], hv, dv);
                    hh[r] = f2h(hv);
                    d1T[n0 + r][mrow] = f2h(dv);
                }
                *(u16x4*)&h1H[mrow][n0] = hh;
            }
        }
        __syncthreads();

        // ---- B: u2 = h1 @ w2 + b2, N=208, K=224 ----
        {
            f16x8 F[7];
            #pragma unroll
            for (int kx = 0; kx < 7; ++kx)
                F[kx] = *(const f16x8*)&h1H[mrow][kx * 32 + lg8];
            for (int nt = ng; nt < 13; nt += 4) {
                f32x4 acc = {0.f, 0.f, 0.f, 0.f};
                const f16x8* wp = W2T + (size_t)nt * 7 * 64 + lane;
                #pragma unroll
                for (int kx = 0; kx < 7; ++kx)
                    acc = __builtin_amdgcn_mfma_f32_16x16x32_f16(wp[kx * 64], F[kx], acc, 0, 0, 0);
                const int n0 = nt * 16 + lg * 4;
                u16x4 hh;
                #pragma unroll
                for (int r = 0; r < 4; ++r) {
                    float hv, dv;
                    gelu_pair(acc[r] + b2L[n0 + r], hv, dv);
                    hh[r] = f2h(hv);
                    d2T[n0 + r][mrow] = f2h(dv);
                }
                *(u16x4*)&h2H[mrow][n0] = hh;
            }
        }
        __syncthreads();

        // ---- C: logits = h2 @ w3, N=32(y<20), K=224, 8 waves split-K x2 ----
        {
            const int mtC = w & 1, ntC = (w >> 1) & 1, kc = w >> 2;
            const int mrowC = mtC * 16 + lr;
            const int kxa = kc ? 4 : 0, kxb = kc ? 7 : 4;
            f32x4 acc = {0.f, 0.f, 0.f, 0.f};
            for (int kx = kxa; kx < kxb; ++kx) {
                f16x8 F = *(const f16x8*)&h2H[mrowC][kx * 32 + lg8];
                acc = __builtin_amdgcn_mfma_f32_16x16x32_f16(W3T[(ntC * 7 + kx) * 64 + lane], F, acc, 0, 0, 0);
            }
            const int n0 = ntC * 16 + lg * 4;
            #pragma unroll
            for (int r = 0; r < 4; ++r) {
                int y = n0 + r;
                if (y < 20) logitsP[kc][y][mrowC] = acc[r];
            }
        }
        __syncthreads();

        // ---- softmax: g3 = -softmax(logits) (fp16) ----
        if (tid < 32) {
            const int s = tid;
            float l[20];
            float m = -1e30f;
            #pragma unroll
            for (int y = 0; y < 20; ++y) {
                float v = b3L[y] + logitsP[0][y][s] + logitsP[1][y][s];
                l[y] = v;
                m = fmaxf(m, v);
            }
            float sum = 0.f;
            #pragma unroll
            for (int y = 0; y < 20; ++y) { l[y] = __expf(l[y] - m); sum += l[y]; }
            float inv = -1.0f / sum;
            #pragma unroll
            for (int y = 0; y < 32; ++y)
                g3H[s][y] = f2h((y < 20) ? l[y] * inv : 0.f);
        }
        __syncthreads();

        // ---- D: dh2 = (g3 @ w3^T) * d2, N=208, K=32 -> h1H ----
        {
            f16x8 B = *(const f16x8*)&g3H[mrow][lg8];
            for (int nt = ng; nt < 13; nt += 4) {
                f32x4 acc = {0.f, 0.f, 0.f, 0.f};
                acc = __builtin_amdgcn_mfma_f32_16x16x32_f16(W3D[nt * 64 + lane], B, acc, 0, 0, 0);
                const int n0 = nt * 16 + lg * 4;
                u16x4 vh;
                #pragma unroll
                for (int r = 0; r < 4; ++r)
                    vh[r] = f2h(acc[r] * h2f(d2T[n0 + r][mrow]));
                *(u16x4*)&h1H[mrow][n0] = vh;
            }
        }
        __syncthreads();

        // ---- E: dh1 = (dh2 @ w2^T) * d1, N=208, K=224 -> h2H ----
        {
            f16x8 F[7];
            #pragma unroll
            for (int kx = 0; kx < 7; ++kx)
                F[kx] = *(const f16x8*)&h1H[mrow][kx * 32 + lg8];
            for (int nt = ng; nt < 13; nt += 4) {
                f32x4 acc = {0.f, 0.f, 0.f, 0.f};
                const f16x8* wp = W2D + (size_t)nt * 7 * 64 + lane;
                #pragma unroll
                for (int kx = 0; kx < 7; ++kx)
                    acc = __builtin_amdgcn_mfma_f32_16x16x32_f16(wp[kx * 64], F[kx], acc, 0, 0, 0);
                const int n0 = nt * 16 + lg * 4;
                u16x4 vh;
                #pragma unroll
                for (int r = 0; r < 4; ++r)
                    vh[r] = f2h(acc[r] * h2f(d1T[n0 + r][mrow]));
                *(u16x4*)&h2H[mrow][n0] = vh;
            }
        }
        __syncthreads();

        // ---- F: gz = dh1 @ w1[:16]^T, N=16, K=224, 8 waves split-K x4 ----
        {
            const int mtF = w & 1, kc = w >> 1;          // kc 0..3
            const int mrowF = mtF * 16 + lr;
            const int kxa = kc * 2;
            const int kxb = (kxa + 2 < 7) ? kxa + 2 : 7;
            f32x4 acc = {0.f, 0.f, 0.f, 0.f};
            for (int kx = kxa; kx < kxb; ++kx) {
                f16x8 F = *(const f16x8*)&h2H[mrowF][kx * 32 + lg8];
                acc = __builtin_amdgcn_mfma_f32_16x16x32_f16(W1D[kx * 64 + lane], F, acc, 0, 0, 0);
            }
            #pragma unroll
            for (int r = 0; r < 4; ++r)
                gzP[kc][lg * 4 + r][mrowF] = acc[r];
        }
        __syncthreads();

        // ---- update z (fp32 state; refresh hi/lo fp16 input) ----
        {
            float g = gzP[0][i16][s16] + gzP[1][i16][s16]
                    + gzP[2][i16][s16] + gzP[3][i16][s16];
            float z = zF[s16][i16];
            float zn = z - 0.08f * (g + 0.25f * z) + 0.4f * eps;
            zF[s16][i16] = zn;
            unsigned short zh = f2h(zn);
            zcH[s16][i16] = zh;
            zcL[s16][i16] = f2h(zn - h2f(zh));
            eps = eps_next;
        }
        __syncthreads();
    }

    zout[(size_t)(gbase + s16) * 16 + i16] = zF[s16][i16];
}

// ---------------- Decoder: bf16 MFMA, 32 samples/wg, 512 threads (R4) -------------
__global__ __launch_bounds__(512) void decoder_kernel(
    const float* __restrict__ ftraj, const float* __restrict__ zfin,
    const unsigned short* __restrict__ wT1, const unsigned short* __restrict__ wT2,
    const unsigned short* __restrict__ wT3, const unsigned short* __restrict__ wT4,
    const float* __restrict__ b1, const float* __restrict__ b2,
    const float* __restrict__ b3, const float* __restrict__ b4,
    float* __restrict__ out)
{
    __shared__ __align__(16) unsigned short xh[32][40];
    __shared__ __align__(16) unsigned short xl[32][40];
    __shared__ __align__(16) unsigned short hA[32][1032];
    __shared__ __align__(16) unsigned short hB[32][520];
    __shared__ float b1L[1024], b2L[512], b3L[1024];

    const int tid = threadIdx.x;
    const int gbase = blockIdx.x * 32;
    const int wv = tid >> 6, l = tid & 63;
    const int lr = l & 15, lg = l >> 4;

    for (int i = tid; i < 1024; i += 512) { b1L[i] = b1[i]; b3L[i] = b3[i]; }
    if (tid < 512) b2L[tid] = b2[tid];
    {
        int s = tid >> 4, c = tid & 15;
        float vf = ftraj[(size_t)(gbase + s) * 16 + c];
        unsigned short fh = f2bf(vf);
        xh[s][c] = fh;
        xl[s][c] = f2bf(vf - bf2f(fh));
        float vz = zfin[(size_t)(gbase + s) * 16 + c];
        unsigned short zh = f2bf(vz);
        xh[s][16 + c] = zh;
        xl[s][16 + c] = f2bf(vz - bf2f(zh));
    }
    __syncthreads();

    // L1: 32 -> 1024, hi/lo split input
    {
        bf16x8 xhf[2], xlf[2];
        #pragma unroll
        for (int mt = 0; mt < 2; ++mt) {
            xhf[mt] = *(const bf16x8*)&xh[mt * 16 + lr][lg * 8];
            xlf[mt] = *(const bf16x8*)&xl[mt * 16 + lr][lg * 8];
        }
        #pragma unroll 2
        for (int a = 0; a < 8; ++a) {
            const int nt = wv * 8 + a;
            bf16x8 af = *(const bf16x8*)&wT1[(size_t)(nt * 16 + lr) * 40 + lg * 8];
            f32x4 acc0 = {0.f, 0.f, 0.f, 0.f}, acc1 = {0.f, 0.f, 0.f, 0.f};
            acc0 = __builtin_amdgcn_mfma_f32_16x16x32_bf16(af, xhf[0], acc0, 0, 0, 0);
            acc0 = __builtin_amdgcn_mfma_f32_16x16x32_bf16(af, xlf[0], acc0, 0, 0, 0);
            acc1 = __builtin_amdgcn_mfma_f32_16x16x32_bf16(af, xhf[1], acc1, 0, 0, 0);
            acc1 = __builtin_amdgcn_mfma_f32_16x16x32_bf16(af, xlf[1], acc1, 0, 0, 0);
            const int n0 = nt * 16 + lg * 4;
            u16x4 o0, o1;
            #pragma unroll
            for (int r = 0; r < 4; ++r) {
                float bb = b1L[n0 + r];
                o0[r] = f2bf(fmaxf(acc0[r] + bb, 0.f));
                o1[r] = f2bf(fmaxf(acc1[r] + bb, 0.f));
            }
            *(u16x4*)&hA[lr][n0] = o0;
            *(u16x4*)&hA[16 + lr][n0] = o1;
        }
    }
    __syncthreads();

    // L2: 1024 -> 512
    {
        f32x4 acc[4][2];
        #pragma unroll
        for (int a = 0; a < 4; ++a)
            #pragma unroll
            for (int mt = 0; mt < 2; ++mt) acc[a][mt] = (f32x4){0.f, 0.f, 0.f, 0.f};
        #pragma unroll 2
        for (int ks = 0; ks < 32; ++ks) {
            const int k0 = ks * 32;
            bf16x8 bfr[2];
            #pragma unroll
            for (int mt = 0; mt < 2; ++mt)
                bfr[mt] = *(const bf16x8*)&hA[mt * 16 + lr][k0 + lg * 8];
            #pragma unroll
            for (int a = 0; a < 4; ++a) {
                const int n = (wv * 4 + a) * 16 + lr;
                bf16x8 af = *(const bf16x8*)&wT2[(size_t)n * 1032 + k0 + lg * 8];
                acc[a][0] = __builtin_amdgcn_mfma_f32_16x16x32_bf16(af, bfr[0], acc[a][0], 0, 0, 0);
                acc[a][1] = __builtin_amdgcn_mfma_f32_16x16x32_bf16(af, bfr[1], acc[a][1], 0, 0, 0);
            }
        }
        #pragma unroll
        for (int a = 0; a < 4; ++a) {
            const int n0 = (wv * 4 + a) * 16 + lg * 4;
            #pragma unroll
            for (int mt = 0; mt < 2; ++mt) {
                u16x4 o;
                #pragma unroll
                for (int r = 0; r < 4; ++r)
                    o[r] = f2bf(fmaxf(acc[a][mt][r] + b2L[n0 + r], 0.f));
                *(u16x4*)&hB[mt * 16 + lr][n0] = o;
            }
        }
    }
    __syncthreads();

    // L3: 512 -> 1024
    {
        f32x4 acc[8][2];
        #pragma unroll
        for (int a = 0; a < 8; ++a)
            #pragma unroll
            for (int mt = 0; mt < 2; ++mt) acc[a][mt] = (f32x4){0.f, 0.f, 0.f, 0.f};
        #pragma unroll 1
        for (int ks = 0; ks < 16; ++ks) {
            const int k0 = ks * 32;
            bf16x8 bfr[2];
            #pragma unroll
            for (int mt = 0; mt < 2; ++mt)
                bfr[mt] = *(const bf16x8*)&hB[mt * 16 + lr][k0 + lg * 8];
            #pragma unroll
            for (int a = 0; a < 8; ++a) {
                const int n = (wv * 8 + a) * 16 + lr;
                bf16x8 af = *(const bf16x8*)&wT3[(size_t)n * 520 + k0 + lg * 8];
                acc[a][0] = __builtin_amdgcn_mfma_f32_16x16x32_bf16(af, bfr[0], acc[a][0], 0, 0, 0);
                acc[a][1] = __builtin_amdgcn_mfma_f32_16x16x32_bf16(af, bfr[1], acc[a][1], 0, 0, 0);
            }
        }
        #pragma unroll
        for (int a = 0; a < 8; ++a) {
            const int n0 = (wv * 8 + a) * 16 + lg * 4;
            #pragma unroll
            for (int mt = 0; mt < 2; ++mt) {
                u16x4 o;
                #pragma unroll
                for (int r = 0; r < 4; ++r)
                    o[r] = f2bf(fmaxf(acc[a][mt][r] + b3L[n0 + r], 0.f));
                *(u16x4*)&hA[mt * 16 + lr][n0] = o;
            }
        }
    }
    __syncthreads();

    // L4: 1024 -> 10(pad 16), split-K over 8 waves
    float* pf = (float*)hB;
    {
        f32x4 acc[2];
        acc[0] = (f32x4){0.f, 0.f, 0.f, 0.f};
        acc[1] = (f32x4){0.f, 0.f, 0.f, 0.f};
        #pragma unroll
        for (int q = 0; q < 4; ++q) {
            const int k0 = (wv * 4 + q) * 32;
            bf16x8 af = *(const bf16x8*)&wT4[(size_t)lr * 1032 + k0 + lg * 8];
            #pragma unroll
            for (int mt = 0; mt < 2; ++mt) {
                bf16x8 bfr = *(const bf16x8*)&hA[mt * 16 + lr][k0 + lg * 8];
                acc[mt] = __builtin_amdgcn_mfma_f32_16x16x32_bf16(af, bfr, acc[mt], 0, 0, 0);
            }
        }
        #pragma unroll
        for (int mt = 0; mt < 2; ++mt)
            *(f32x4*)&pf[((wv * 2 + mt) * 64 + l) * 4] = acc[mt];
    }
    __syncthreads();
    {
        const int m = tid & 31, n = tid >> 5;
        const int lsrc = ((n >> 2) << 4) | (m & 15);
        const int r = n & 3, mt = m >> 4;
        float v = 0.f;
        #pragma unroll
        for (int ww = 0; ww < 8; ++ww)
            v += pf[((ww * 2 + mt) * 64 + lsrc) * 4 + r];
        if (n < 10)
            out[(size_t)(gbase + m) * 10 + n] = v + b4[n];
    }
}

__global__ void copy_ftraj_kernel(const float4* __restrict__ src, float4* __restrict__ dst) {
    int idx = blockIdx.x * blockDim.x + threadIdx.x;
    dst[idx] = src[idx];
}

extern "C" void kernel_launch(void* const* d_in, const int* in_sizes, int n_in,
                              void* d_out, int out_size, void* d_ws, size_t ws_size,
                              hipStream_t stream)
{
    const float* ftraj = (const float*)d_in[0];
    const float* z0    = (const float*)d_in[1];
    const float* noise = (const float*)d_in[2];
    const float* ew1 = (const float*)d_in[3];
    const float* eb1 = (const float*)d_in[4];
    const float* ew2 = (const float*)d_in[5];
    const float* eb2 = (const float*)d_in[6];
    const float* ew3 = (const float*)d_in[7];
    const float* eb3 = (const float*)d_in[8];
    const float* dw1 = (const float*)d_in[9];
    const float* db1 = (const float*)d_in[10];
    const float* dw2 = (const float*)d_in[11];
    const float* db2 = (const float*)d_in[12];
    const float* dw3 = (const float*)d_in[13];
    const float* db3 = (const float*)d_in[14];
    const float* dw4 = (const float*)d_in[15];
    const float* db4 = (const float*)d_in[16];
    float* out = (float*)d_out;

    char* ws = (char*)d_ws;
    float* zfin           = (float*)ws;                           // 4 MB
    unsigned short* w1tp  = (unsigned short*)(ws + 4194304);      // 13312 B
    unsigned short* w2tp  = (unsigned short*)(ws + 4210688);      // 93184 B
    unsigned short* w2dp  = (unsigned short*)(ws + 4308992);      // 93184 B
    unsigned short* w3tp  = (unsigned short*)(ws + 4407296);      // 14336 B
    unsigned short* w3dp  = (unsigned short*)(ws + 4423680);      // 13312 B
    unsigned short* w1dp  = (unsigned short*)(ws + 4440064);      // 7168 B
    unsigned short* wsT1  = (unsigned short*)(ws + 4448256);      // 81920 B
    unsigned short* wsT2  = (unsigned short*)(ws + 4530176);      // 1056768 B
    unsigned short* wsT3  = (unsigned short*)(ws + 5586944);      // 1064960 B
    unsigned short* wsT4  = (unsigned short*)(ws + 6651904);      // 33024 B

    // EBM packed fp16 weight fragments:
    // A: w1^T[j][kin]  (src ew1[kin][j], transposed)      NT=13 KT=1
    pack_w<<<(13*1*512 + 511)/512, 512, 0, stream>>>(ew1, w1tp, 32, 200, 1, 13, 1);
    // B: w2^T[j2][k1]  (src ew2[k1][j2], transposed)      NT=13 KT=7
    pack_w<<<(13*7*512 + 511)/512, 512, 0, stream>>>(ew2, w2tp, 200, 200, 1, 13, 7);
    // E: w2[i][k2]     (src ew2 direct)                   NT=13 KT=7
    pack_w<<<(13*7*512 + 511)/512, 512, 0, stream>>>(ew2, w2dp, 200, 200, 0, 13, 7);
    // C: w3^T[y][k2]   (src ew3[k2][y], transposed)       NT=2  KT=7
    pack_w<<<(2*7*512 + 511)/512, 512, 0, stream>>>(ew3, w3tp, 200, 20, 1, 2, 7);
    // D: w3[k2][y]     (src ew3 direct)                   NT=13 KT=1
    pack_w<<<(13*1*512 + 511)/512, 512, 0, stream>>>(ew3, w3dp, 200, 20, 0, 13, 1);
    // F: w1[i][k1]     (src ew1 direct)                   NT=1  KT=7
    pack_w<<<(1*7*512 + 511)/512, 512, 0, stream>>>(ew1, w1dp, 32, 200, 0, 1, 7);
    // decoder weights (bf16):
    prep_wT_kernel<<<(1024*40 + 511)/512, 512, 0, stream>>>(dw1, wsT1, 32, 40, 1024, 1024);
    prep_wT_kernel<<<(512*1032 + 511)/512, 512, 0, stream>>>(dw2, wsT2, 1024, 1032, 512, 512);
    prep_wT_kernel<<<(1024*520 + 511)/512, 512, 0, stream>>>(dw3, wsT3, 512, 520, 1024, 1024);
    prep_wT_kernel<<<(16*1032 + 511)/512, 512, 0, stream>>>(dw4, wsT4, 1024, 1032, 10, 16);

    langevin_kernel<<<NTOT / 32, 512, 0, stream>>>(
        ftraj, z0, noise,
        w1tp, w2tp, w2dp, w3tp, w3dp, w1dp,
        eb1, eb2, eb3, zfin);
    decoder_kernel<<<NTOT / 32, 512, 0, stream>>>(ftraj, zfin,
                                                  wsT1, wsT2, wsT3, wsT4,
                                                  db1, db2, db3, db4, out);
    copy_ftraj_kernel<<<512, 512, 0, stream>>>((const float4*)ftraj,
                                               (float4*)(out + (size_t)NTOT * 10));
}